// Round 8
// baseline (186.232 us; speedup 1.0000x reference)
//
#include <hip/hip_runtime.h>

// Propagation: E = softsign(V V^T / sqrt(D)); out0 = E @ state; out1 = E @ V
// B=4, N=4096, D=256, fp32 in/out.
//
// Round 8 (R6 base + two LDS cuts):
//  - GEMM1 computes S^T (A=vj from LDS, B=Vi registers; swap validated in R7):
//    lane holds fixed-i / 4-consecutive-j -> Esh writes become 4x ds_write_b64
//    (vs 16x b16). Esh stays row-major [i][j] so GEMM2 reads are unchanged b128.
//  - GEMM1 wave shape 64i x 16j (8 waves = 2 i-halves x 4 j-quarters): vj
//    fragment reads halve (8 b128/wave/iter); Vi register frags 128 VGPRs.
//  - Everything else R6 verbatim: 2 barriers/iter, vjt dbuf + vj single,
//    Esh dbuf, shared j-tile, grid 256 = b x 32it(128 rows) x 2 jh, partials
//    in ws + combine kernel.
//  - fallback: round-1 fused kernel if ws too small.

#define B_  4
#define N_  4096
#define D_  256

typedef __attribute__((ext_vector_type(8))) short short8;
typedef __attribute__((ext_vector_type(4))) float floatx4;

__device__ __forceinline__ unsigned short f2bf(float f) {
    unsigned int u = __float_as_uint(f);
    u += 0x7fff + ((u >> 16) & 1);   // RTNE
    return (unsigned short)(u >> 16);
}

__device__ __forceinline__ void gl_lds16(const void* g, void* l) {
    __builtin_amdgcn_global_load_lds(
        (const __attribute__((address_space(1))) unsigned int*)g,
        (__attribute__((address_space(3))) unsigned int*)l, 16, 0, 0);
}
__device__ __forceinline__ void gl_lds4(const void* g, void* l) {
    __builtin_amdgcn_global_load_lds(
        (const __attribute__((address_space(1))) unsigned int*)g,
        (__attribute__((address_space(3))) unsigned int*)l, 4, 0, 0);
}

// ---------------- pre-pass: fp32 -> bf16, plus transpose ----------------
__global__ __launch_bounds__(256)
void prepass_kernel(const float* __restrict__ val,
                    unsigned short* __restrict__ Vb,
                    unsigned short* __restrict__ VT) {
    __shared__ unsigned short tile[64][68];
    const int t   = threadIdx.x;
    const int blk = blockIdx.x;            // b*256 + it*4 + dt
    const int b   = blk >> 8;
    const int it  = (blk >> 2) & 63;
    const int dt  = blk & 3;
    const int i0  = it * 64, d0 = dt * 64;
    const float*    vb  = val + (size_t)b * N_ * D_;
    unsigned short* Vbb = Vb  + (size_t)b * N_ * D_;
    unsigned short* VTb = VT  + (size_t)b * D_ * N_;

    #pragma unroll
    for (int q = 0; q < 4; ++q) {
        int idx = t + 256 * q;
        int row = idx >> 4;
        int c4  = idx & 15;
        float4 v = *(const float4*)(vb + (size_t)(i0 + row) * D_ + d0 + c4 * 4);
        ushort4 h;
        h.x = f2bf(v.x); h.y = f2bf(v.y); h.z = f2bf(v.z); h.w = f2bf(v.w);
        *(ushort4*)(Vbb + (size_t)(i0 + row) * D_ + d0 + c4 * 4) = h;
        *(ushort4*)&tile[row][c4 * 4] = h;
    }
    __syncthreads();
    #pragma unroll
    for (int q = 0; q < 4; ++q) {
        int dr = (t >> 4) + q * 16;
        int i4 = t & 15;
        ushort4 h;
        h.x = tile[i4 * 4 + 0][dr];
        h.y = tile[i4 * 4 + 1][dr];
        h.z = tile[i4 * 4 + 2][dr];
        h.w = tile[i4 * 4 + 3][dr];
        *(ushort4*)(VTb + (size_t)(d0 + dr) * N_ + i0 + i4 * 4) = h;
    }
}

// ---------------- main fused kernel ----------------
// grid 256 = b(4) x it(32, 128-row tiles) x jh(2).  512 threads, 8 waves:
// group g = i-half (64 rows).  GEMM1: wave w4 covers j-quarter jq=w4*16,
// all 64 i of its group (S^T, Vi in 128 VGPRs). GEMM2: wave w4 covers
// d-slice w4*64, all 64 i of its group (R6 verbatim).
// LDS map (bytes), total 137472:
//   vjt  : 0      + buf*32768   (2 x 32768)  [256 d][64 j] granule-swizzled
//   vj   : 65536               (32768)       [64 j][256 d] granule-swizzled
//   Esh  : 98304  + g*18432 + buf*9216       (2 g x 2 buf x 64 x 72 bf16)
//   stj  : 135168              (256)         64 f32
//   dsred: 135424 + g*1024     (2 x 1024)    [w4][64] f32 per group
__global__ __launch_bounds__(512, 2)
void prop_main(const float* __restrict__ state,
               const unsigned short* __restrict__ Vb,
               const unsigned short* __restrict__ VT,
               float* __restrict__ dvp,   // [2][B][N][D] partials
               float* __restrict__ dsp_o) // [2][B][N]    partials
{
    __shared__ __attribute__((aligned(16))) unsigned char smem[137472];

    const int t    = threadIdx.x;
    const int g    = t >> 8;          // wave-group (i-half) 0/1
    const int w    = t >> 6;          // wave 0..7
    const int w4   = w & 3;           // wave within group
    const int lane = t & 63;
    const int quad = lane >> 4;
    const int l16  = lane & 15;

    const int x   = blockIdx.x;
    const int b   = x >> 6;
    const int it  = (x >> 1) & 31;
    const int jh  = x & 1;
    const int it0 = it * 128;
    const int jbase = jh * 2048;
    const int niter = 32;

    unsigned short* vjL  = (unsigned short*)(smem + 65536);
    float*          stjL = (float*)(smem + 135168);
    float*          dsredg = (float*)(smem + 135424 + g * 1024);

    const unsigned short* Vbb = Vb + (size_t)b * N_ * D_;
    const unsigned short* VTb = VT + (size_t)b * D_ * N_;
    const float*          stb = state + (size_t)b * N_;

    const int hi  = lane >> 5;
    const int p32 = lane & 31;
    const int dr8 = lane >> 3;
    const int p8  = lane & 7;

    // per-wave staging offsets (8 waves cooperatively stage the shared tile)
    int vgoff[4];   // vj: rows 2*(w*4+n)+hi, granule-swizzled
    int tgoff[4];   // vjt: d-rows 8*(w*4+n)+dr8
    #pragma unroll
    for (int n = 0; n < 4; ++n) {
        int r  = 2 * (w * 4 + n) + hi;           // 0..63
        vgoff[n] = r * 256 + (p32 ^ (r & 7)) * 8;
        int d  = 8 * (w * 4 + n) + dr8;          // 0..255
        tgoff[n] = d * 4096 + (p8 ^ dr8) * 8;
    }

    const int jq = w4 * 16;           // GEMM1 j-quarter base (within 64-tile)
    const int pA = l16 & 7;

    // ---- Vi fragments in registers: GEMM1 B-operand, 64 i rows ----
    // Vi4[ib][ks]: row it0+g*64+ib*16+l16, k-chunk ks*32+quad*8 (128 VGPRs)
    short8 Vi4[4][8];
    #pragma unroll
    for (int ib = 0; ib < 4; ++ib) {
        const unsigned short* ar =
            Vbb + (size_t)(it0 + g * 64 + ib * 16 + l16) * 256 + quad * 8;
        #pragma unroll
        for (int ks = 0; ks < 8; ++ks)
            Vi4[ib][ks] = *(const short8*)(ar + ks * 32);
    }

    // ---- prologue: stage tile 0 (vjt->buf0, vj, stj) ----
    #pragma unroll
    for (int n = 0; n < 4; ++n)
        gl_lds16(VTb + (size_t)jbase + tgoff[n], smem + (w * 4 + n) * 1024);
    #pragma unroll
    for (int n = 0; n < 4; ++n)
        gl_lds16(Vbb + (size_t)jbase * 256 + vgoff[n],
                 smem + 65536 + (w * 4 + n) * 1024);
    if (w == 0) gl_lds4(stb + jbase + lane, stjL);

    floatx4 dv[4][4];                 // GEMM2 acc (R6): [i-tile][d-tile]
    #pragma unroll
    for (int a = 0; a < 4; ++a)
        #pragma unroll
        for (int c = 0; c < 4; ++c)
            dv[a][c] = (floatx4){0.f, 0.f, 0.f, 0.f};
    float dsp[4] = {0.f, 0.f, 0.f, 0.f};   // [ib]: i = ib*16+l16

    for (int k = 0; k < niter; ++k) {
        const int buf = k & 1;
        unsigned short* Eshg = (unsigned short*)(smem + 98304 + g * 18432 + buf * 9216);
        unsigned short* vjtg = (unsigned short*)(smem + buf * 32768);

        __syncthreads();   // B1: vjt[buf](k), vj(k), stj(k) visible

        // ---- stage vjt(k+1) into the other buffer ----
        if (k + 1 < niter) {
            const size_t j0n = jbase + (size_t)(k + 1) * 64;
            #pragma unroll
            for (int n = 0; n < 4; ++n)
                gl_lds16(VTb + j0n + tgoff[n],
                         smem + (buf ^ 1) * 32768 + (w * 4 + n) * 1024);
        }

        // ---- GEMM1 (swapped): S^T[jq..jq+16)[64 i] = Vj . Vi^T ----
        floatx4 sa[4];                // [ib]
        #pragma unroll
        for (int ib = 0; ib < 4; ++ib)
            sa[ib] = (floatx4){0.f, 0.f, 0.f, 0.f};

        #pragma unroll
        for (int ks = 0; ks < 8; ++ks) {
            const int p = ((ks * 4 + quad) ^ pA) * 8;
            short8 aj = *(const short8*)&vjL[(jq + l16) * 256 + p];
            sa[0] = __builtin_amdgcn_mfma_f32_16x16x32_bf16(aj, Vi4[0][ks], sa[0], 0, 0, 0);
            sa[1] = __builtin_amdgcn_mfma_f32_16x16x32_bf16(aj, Vi4[1][ks], sa[1], 0, 0, 0);
            sa[2] = __builtin_amdgcn_mfma_f32_16x16x32_bf16(aj, Vi4[2][ks], sa[2], 0, 0, 0);
            sa[3] = __builtin_amdgcn_mfma_f32_16x16x32_bf16(aj, Vi4[3][ks], sa[3], 0, 0, 0);
        }

        // ---- softsign epilogue: e = s/(16+|s|) -> Esh b64 writes + ds ----
        // lane holds E[i = ib*16+l16][j = jq+quad*4+r]
        float4 st4 = *(const float4*)&stjL[jq + quad * 4];
        #pragma unroll
        for (int ib = 0; ib < 4; ++ib) {
            float e0 = sa[ib][0] * __builtin_amdgcn_rcpf(16.0f + fabsf(sa[ib][0]));
            float e1 = sa[ib][1] * __builtin_amdgcn_rcpf(16.0f + fabsf(sa[ib][1]));
            float e2 = sa[ib][2] * __builtin_amdgcn_rcpf(16.0f + fabsf(sa[ib][2]));
            float e3 = sa[ib][3] * __builtin_amdgcn_rcpf(16.0f + fabsf(sa[ib][3]));
            dsp[ib] += e0 * st4.x + e1 * st4.y + e2 * st4.z + e3 * st4.w;
            uint2 pk;
            pk.x = (unsigned int)f2bf(e0) | ((unsigned int)f2bf(e1) << 16);
            pk.y = (unsigned int)f2bf(e2) | ((unsigned int)f2bf(e3) << 16);
            *(uint2*)&Eshg[(ib * 16 + l16) * 72 + jq + quad * 4] = pk;
        }
        __syncthreads();   // B2: Esh[buf] visible; vj/stj consumed; vjt DMA drained

        // ---- stage vj(k+1)/stj(k+1) (single buffer; window: GEMM2) ----
        if (k + 1 < niter) {
            const size_t j0n = jbase + (size_t)(k + 1) * 64;
            #pragma unroll
            for (int n = 0; n < 4; ++n)
                gl_lds16(Vbb + j0n * 256 + vgoff[n],
                         smem + 65536 + (w * 4 + n) * 1024);
            if (w == 0) gl_lds4(stb + j0n + lane, stjL);
        }

        // ---- GEMM2: dval += E . Vj (A from Esh[buf], B from vjt[buf]) ----
        #pragma unroll
        for (int ks = 0; ks < 2; ++ks) {
            short8 af[4], bfr[4];
            #pragma unroll
            for (int a2 = 0; a2 < 4; ++a2)
                af[a2] = *(const short8*)&Eshg[(a2 * 16 + l16) * 72 + ks * 32 + quad * 8];
            #pragma unroll
            for (int c2 = 0; c2 < 4; ++c2) {
                const int d = w4 * 64 + c2 * 16 + l16;
                const int p = ((ks * 4 + quad) ^ pA) * 8;
                bfr[c2] = *(const short8*)&vjtg[d * 64 + p];
            }
            #pragma unroll
            for (int a2 = 0; a2 < 4; ++a2)
                #pragma unroll
                for (int c2 = 0; c2 < 4; ++c2)
                    dv[a2][c2] = __builtin_amdgcn_mfma_f32_16x16x32_bf16(af[a2], bfr[c2], dv[a2][c2], 0, 0, 0);
        }
        // next barrier is B1 of iter k+1
    }

    // ---- epilogue: partial delta_val (R6 verbatim) ----
    float* dvo = dvp + (size_t)jh * B_ * N_ * D_ + (size_t)b * N_ * D_
                     + (size_t)(it0 + g * 64) * D_;
    #pragma unroll
    for (int a2 = 0; a2 < 4; ++a2)
        #pragma unroll
        for (int c2 = 0; c2 < 4; ++c2)
            #pragma unroll
            for (int r = 0; r < 4; ++r) {
                const int il = a2 * 16 + quad * 4 + r;
                const int d  = w4 * 64 + c2 * 16 + l16;
                dvo[(size_t)il * D_ + d] = dv[a2][c2][r];
            }

    // ---- epilogue: partial delta_state ----
    // dsp[ib] covers i=ib*16+l16 over this wave's 16 j; sum quads first.
    #pragma unroll
    for (int ib = 0; ib < 4; ++ib) {
        float v = dsp[ib];
        v += __shfl_xor(v, 16);
        v += __shfl_xor(v, 32);
        dsp[ib] = v;
    }
    if (quad == 0) {
        #pragma unroll
        for (int ib = 0; ib < 4; ++ib)
            dsredg[w4 * 64 + ib * 16 + l16] = dsp[ib];
    }
    __syncthreads();
    if (t < 128) {
        const int gg = t >> 6;
        const int i  = t & 63;
        const float* dsr = (const float*)(smem + 135424 + gg * 1024);
        dsp_o[(size_t)jh * B_ * N_ + (size_t)b * N_ + it0 + gg * 64 + i]
            = dsr[i] + dsr[64 + i] + dsr[128 + i] + dsr[192 + i];
    }
}

// ---------------- combine: out = sum of the two j-half partials ----------------
__global__ __launch_bounds__(256)
void combine_kernel(const float4* __restrict__ dv0, const float4* __restrict__ dv1,
                    const float*  __restrict__ ds0, const float*  __restrict__ ds1,
                    float* __restrict__ out) {
    const int NDV4 = B_ * N_ * D_ / 4;   // 1048576
    const int NDS  = B_ * N_;            // 16384
    int x = blockIdx.x * 256 + threadIdx.x;
    if (x < NDV4) {
        float4 a = dv0[x], c = dv1[x];
        float4 r;
        r.x = a.x + c.x; r.y = a.y + c.y; r.z = a.z + c.z; r.w = a.w + c.w;
        ((float4*)(out + NDS))[x] = r;
    } else {
        int y = (x - NDV4) * 4;
        if (y < NDS) {
            float4 a = *(const float4*)(ds0 + y);
            float4 c = *(const float4*)(ds1 + y);
            float4 r;
            r.x = a.x + c.x; r.y = a.y + c.y; r.z = a.z + c.z; r.w = a.w + c.w;
            *(float4*)(out + y) = r;
        }
    }
}

// ---------------- fallback (round-1 kernel, used if ws too small) ----------------
__global__ __launch_bounds__(256, 1)
void prop_kernel_fb(const float* __restrict__ val,
                    const float* __restrict__ state,
                    float* __restrict__ out) {
    __shared__ __attribute__((aligned(16))) unsigned short vi[64][264];
    __shared__ __attribute__((aligned(16))) unsigned short vj[64][264];
    __shared__ __attribute__((aligned(16))) unsigned short vjt[2048][8];
    __shared__ __attribute__((aligned(16))) unsigned short Esh[64][72];
    __shared__ float stj[64];
    __shared__ float dsred[2][64];

    const int t    = threadIdx.x;
    const int w    = t >> 6;
    const int lane = t & 63;
    const int quad = lane >> 4;
    const int l16  = lane & 15;
    const int b   = blockIdx.x >> 6;
    const int it0 = (blockIdx.x & 63) << 6;
    const float* valb = val   + (size_t)b * N_ * D_;
    const float* stb  = state + (size_t)b * N_;

    #pragma unroll
    for (int n = 0; n < 16; ++n) {
        int idx = t + 256 * n;
        int row = idx >> 6;
        int c4  = idx & 63;
        float4 v = *(const float4*)(valb + (size_t)(it0 + row) * D_ + c4 * 4);
        ushort4 h;
        h.x = f2bf(v.x); h.y = f2bf(v.y); h.z = f2bf(v.z); h.w = f2bf(v.w);
        *(ushort4*)&vi[row][c4 * 4] = h;
    }

    const int r0 = (w >> 1) * 32;
    const int c0 = (w & 1) * 32;
    floatx4 dv[4][4];
    #pragma unroll
    for (int a = 0; a < 4; ++a)
        #pragma unroll
        for (int c = 0; c < 4; ++c)
            dv[a][c] = (floatx4){0.f, 0.f, 0.f, 0.f};
    float dsp[8];
    #pragma unroll
    for (int k = 0; k < 8; ++k) dsp[k] = 0.f;

    for (int jt = 0; jt < 64; ++jt) {
        const int j0 = jt * 64;
        #pragma unroll
        for (int n = 0; n < 16; ++n) {
            int idx = t + 256 * n;
            int row = idx >> 6;
            int c4  = idx & 63;
            float4 v = *(const float4*)(valb + (size_t)(j0 + row) * D_ + c4 * 4);
            ushort4 h;
            h.x = f2bf(v.x); h.y = f2bf(v.y); h.z = f2bf(v.z); h.w = f2bf(v.w);
            *(ushort4*)&vj[row][c4 * 4] = h;
        }
        if (t < 64) stj[t] = stb[j0 + t];
        __syncthreads();

        #pragma unroll
        for (int n = 0; n < 8; ++n) {
            const int d  = t;
            const int jb = n;
            short8 pk;
            #pragma unroll
            for (int jj = 0; jj < 8; ++jj) pk[jj] = (short)vj[jb * 8 + jj][d];
            *(short8*)&vjt[d * 8 + (jb ^ (d & 7))][0] = pk;
        }

        floatx4 sa[2][2];
        #pragma unroll
        for (int a = 0; a < 2; ++a)
            #pragma unroll
            for (int c = 0; c < 2; ++c)
                sa[a][c] = (floatx4){0.f, 0.f, 0.f, 0.f};
        #pragma unroll
        for (int ks = 0; ks < 8; ++ks) {
            const int d0 = ks * 32 + quad * 8;
            short8 a0 = *(const short8*)&vi[r0 + l16][d0];
            short8 a1 = *(const short8*)&vi[r0 + 16 + l16][d0];
            short8 b0 = *(const short8*)&vj[c0 + l16][d0];
            short8 b1 = *(const short8*)&vj[c0 + 16 + l16][d0];
            sa[0][0] = __builtin_amdgcn_mfma_f32_16x16x32_bf16(a0, b0, sa[0][0], 0, 0, 0);
            sa[0][1] = __builtin_amdgcn_mfma_f32_16x16x32_bf16(a0, b1, sa[0][1], 0, 0, 0);
            sa[1][0] = __builtin_amdgcn_mfma_f32_16x16x32_bf16(a1, b0, sa[1][0], 0, 0, 0);
            sa[1][1] = __builtin_amdgcn_mfma_f32_16x16x32_bf16(a1, b1, sa[1][1], 0, 0, 0);
        }

        float stc0 = stj[c0 + l16];
        float stc1 = stj[c0 + 16 + l16];
        #pragma unroll
        for (int a = 0; a < 2; ++a) {
            #pragma unroll
            for (int r = 0; r < 4; ++r) {
                const int il = r0 + a * 16 + quad * 4 + r;
                float s0 = sa[a][0][r] * 0.0625f;
                float s1 = sa[a][1][r] * 0.0625f;
                float e0 = s0 / (1.0f + fabsf(s0));
                float e1 = s1 / (1.0f + fabsf(s1));
                dsp[a * 4 + r] += e0 * stc0 + e1 * stc1;
                Esh[il][c0 + l16]      = f2bf(e0);
                Esh[il][c0 + 16 + l16] = f2bf(e1);
            }
        }
        __syncthreads();

        #pragma unroll
        for (int ks = 0; ks < 2; ++ks) {
            short8 af[4], bfr[4];
            #pragma unroll
            for (int a2 = 0; a2 < 4; ++a2)
                af[a2] = *(const short8*)&Esh[a2 * 16 + l16][ks * 32 + quad * 8];
            #pragma unroll
            for (int c2 = 0; c2 < 4; ++c2) {
                const int d  = w * 64 + c2 * 16 + l16;
                const int jb = ks * 4 + quad;
                bfr[c2] = *(const short8*)&vjt[d * 8 + (jb ^ (d & 7))][0];
            }
            #pragma unroll
            for (int a2 = 0; a2 < 4; ++a2)
                #pragma unroll
                for (int c2 = 0; c2 < 4; ++c2)
                    dv[a2][c2] = __builtin_amdgcn_mfma_f32_16x16x32_bf16(af[a2], bfr[c2], dv[a2][c2], 0, 0, 0);
        }
    }

    float* dvo = out + (size_t)B_ * N_ + (size_t)b * N_ * D_;
    #pragma unroll
    for (int a2 = 0; a2 < 4; ++a2)
        #pragma unroll
        for (int c2 = 0; c2 < 4; ++c2)
            #pragma unroll
            for (int r = 0; r < 4; ++r) {
                const int i = it0 + a2 * 16 + quad * 4 + r;
                const int d = w * 64 + c2 * 16 + l16;
                dvo[(size_t)i * D_ + d] = dv[a2][c2][r];
            }

    #pragma unroll
    for (int k = 0; k < 8; ++k) {
        float v = dsp[k];
        v += __shfl_xor(v, 1);
        v += __shfl_xor(v, 2);
        v += __shfl_xor(v, 4);
        v += __shfl_xor(v, 8);
        dsp[k] = v;
    }
    if (l16 == 0) {
        #pragma unroll
        for (int a = 0; a < 2; ++a)
            #pragma unroll
            for (int r = 0; r < 4; ++r) {
                const int row = (w >> 1) * 32 + a * 16 + quad * 4 + r;
                dsred[w & 1][row] = dsp[a * 4 + r];
            }
    }
    __syncthreads();
    if (t < 64) out[(size_t)b * N_ + it0 + t] = dsred[0][t] + dsred[1][t];
}

extern "C" void kernel_launch(void* const* d_in, const int* in_sizes, int n_in,
                              void* d_out, int out_size, void* d_ws, size_t ws_size,
                              hipStream_t stream) {
    const float* val   = (const float*)d_in[0];
    const float* state = (const float*)d_in[1];
    float* out = (float*)d_out;

    const size_t nE         = (size_t)B_ * N_ * D_;                 // 4,194,304
    const size_t need_base  = 2 * nE * sizeof(unsigned short);      // 16.78 MB
    const size_t need_split = need_base + 2 * nE * sizeof(float)
                            + 2 * (size_t)B_ * N_ * sizeof(float);  // ~50.5 MB

    if (ws_size >= need_split) {
        unsigned short* Vb = (unsigned short*)d_ws;
        unsigned short* VT = Vb + nE;
        float* dvp = (float*)(VT + nE);          // [2][B*N*D]
        float* dsp = dvp + 2 * nE;               // [2][B*N]
        prepass_kernel<<<dim3(1024), dim3(256), 0, stream>>>(val, Vb, VT);
        prop_main<<<dim3(256), dim3(512), 0, stream>>>(state, Vb, VT, dvp, dsp);
        const int NDV4 = B_ * N_ * D_ / 4;
        const int NDS4 = B_ * N_ / 4;
        combine_kernel<<<dim3((NDV4 + NDS4) / 256), dim3(256), 0, stream>>>(
            (const float4*)dvp, (const float4*)(dvp + nE),
            dsp, dsp + (size_t)B_ * N_, out);
    } else {
        prop_kernel_fb<<<dim3(256), dim3(256), 0, stream>>>(val, state, out);
    }
}

// Round 9
// 151.517 us; speedup vs baseline: 1.2291x; 1.2291x over previous
//
#include <hip/hip_runtime.h>

// Propagation: E = softsign(V V^T / sqrt(D)); out0 = E @ state; out1 = E @ V
// B=4, N=4096, D=256, fp32 in/out.
//
// Round 9 = R6 + S^T swap ONLY (R8 minus the 128-VGPR Vi blocking that spilled):
//  - GEMM1 computes S^T (A=vj from LDS, B=Vi regs, same 32i x 32j wave shape,
//    64 VGPR Vi). Lane then holds fixed-i / 4-consecutive-j -> Esh epilogue is
//    4x ds_write_b64 instead of 16x ds_write_b16 (kills b16 same-bank write
//    serialization). GEMM1 LDS reads unchanged (= mfma / i-blocks).
//  - Everything else R6 verbatim: 2 barriers/iter, vjt dbuf + vj single, Esh
//    dbuf, shared j-tile, grid 256 = b x 32it(128 rows) x 2 jh, partials in
//    ws + combine kernel.
//  - fallback: round-1 fused kernel if ws too small.

#define B_  4
#define N_  4096
#define D_  256

typedef __attribute__((ext_vector_type(8))) short short8;
typedef __attribute__((ext_vector_type(4))) float floatx4;

__device__ __forceinline__ unsigned short f2bf(float f) {
    unsigned int u = __float_as_uint(f);
    u += 0x7fff + ((u >> 16) & 1);   // RTNE
    return (unsigned short)(u >> 16);
}

__device__ __forceinline__ void gl_lds16(const void* g, void* l) {
    __builtin_amdgcn_global_load_lds(
        (const __attribute__((address_space(1))) unsigned int*)g,
        (__attribute__((address_space(3))) unsigned int*)l, 16, 0, 0);
}
__device__ __forceinline__ void gl_lds4(const void* g, void* l) {
    __builtin_amdgcn_global_load_lds(
        (const __attribute__((address_space(1))) unsigned int*)g,
        (__attribute__((address_space(3))) unsigned int*)l, 4, 0, 0);
}

// ---------------- pre-pass: fp32 -> bf16, plus transpose ----------------
__global__ __launch_bounds__(256)
void prepass_kernel(const float* __restrict__ val,
                    unsigned short* __restrict__ Vb,
                    unsigned short* __restrict__ VT) {
    __shared__ unsigned short tile[64][68];
    const int t   = threadIdx.x;
    const int blk = blockIdx.x;            // b*256 + it*4 + dt
    const int b   = blk >> 8;
    const int it  = (blk >> 2) & 63;
    const int dt  = blk & 3;
    const int i0  = it * 64, d0 = dt * 64;
    const float*    vb  = val + (size_t)b * N_ * D_;
    unsigned short* Vbb = Vb  + (size_t)b * N_ * D_;
    unsigned short* VTb = VT  + (size_t)b * D_ * N_;

    #pragma unroll
    for (int q = 0; q < 4; ++q) {
        int idx = t + 256 * q;
        int row = idx >> 4;
        int c4  = idx & 15;
        float4 v = *(const float4*)(vb + (size_t)(i0 + row) * D_ + d0 + c4 * 4);
        ushort4 h;
        h.x = f2bf(v.x); h.y = f2bf(v.y); h.z = f2bf(v.z); h.w = f2bf(v.w);
        *(ushort4*)(Vbb + (size_t)(i0 + row) * D_ + d0 + c4 * 4) = h;
        *(ushort4*)&tile[row][c4 * 4] = h;
    }
    __syncthreads();
    #pragma unroll
    for (int q = 0; q < 4; ++q) {
        int dr = (t >> 4) + q * 16;
        int i4 = t & 15;
        ushort4 h;
        h.x = tile[i4 * 4 + 0][dr];
        h.y = tile[i4 * 4 + 1][dr];
        h.z = tile[i4 * 4 + 2][dr];
        h.w = tile[i4 * 4 + 3][dr];
        *(ushort4*)(VTb + (size_t)(d0 + dr) * N_ + i0 + i4 * 4) = h;
    }
}

// ---------------- main fused kernel ----------------
// grid 256 = b(4) x it(32, 128-row tiles) x jh(2).  512 threads, 8 waves:
// group g = i-half (64 rows); wave w4: r0=(w4>>1)*32 (i), c0=(w4&1)*32 (j).
// LDS map (bytes), total 136448 (R6):
//   vjt  : 0      + buf*32768   (2 x 32768)  [256 d][64 j] granule-swizzled
//   vj   : 65536               (32768)       [64 j][256 d] granule-swizzled
//   Esh  : 98304  + g*18432 + buf*9216       (2 g x 2 buf x 64 x 72 bf16)
//   stj  : 135168              (256)         64 f32
//   dsred: 135424 + g*512      (2 x 512)     [2][64] f32 per group
__global__ __launch_bounds__(512, 1)
void prop_main(const float* __restrict__ state,
               const unsigned short* __restrict__ Vb,
               const unsigned short* __restrict__ VT,
               float* __restrict__ dvp,   // [2][B][N][D] partials
               float* __restrict__ dsp_o) // [2][B][N]    partials
{
    __shared__ __attribute__((aligned(16))) unsigned char smem[136448];

    const int t    = threadIdx.x;
    const int g    = t >> 8;          // wave-group (i-half) 0/1
    const int w    = t >> 6;          // wave 0..7
    const int w4   = w & 3;           // wave within group
    const int lane = t & 63;
    const int quad = lane >> 4;
    const int l16  = lane & 15;

    const int x   = blockIdx.x;
    const int b   = x >> 6;
    const int it  = (x >> 1) & 31;
    const int jh  = x & 1;
    const int it0 = it * 128;
    const int jbase = jh * 2048;
    const int niter = 32;

    unsigned short* vjL  = (unsigned short*)(smem + 65536);
    float*          stjL = (float*)(smem + 135168);
    float*          dsredg = (float*)(smem + 135424 + g * 512);

    const unsigned short* Vbb = Vb + (size_t)b * N_ * D_;
    const unsigned short* VTb = VT + (size_t)b * D_ * N_;
    const float*          stb = state + (size_t)b * N_;

    const int hi  = lane >> 5;
    const int p32 = lane & 31;
    const int dr8 = lane >> 3;
    const int p8  = lane & 7;

    int vgoff[4];   // vj: rows 2*(w*4+n)+hi, granule-swizzled
    int tgoff[4];   // vjt: d-rows 8*(w*4+n)+dr8
    #pragma unroll
    for (int n = 0; n < 4; ++n) {
        int r  = 2 * (w * 4 + n) + hi;           // 0..63
        vgoff[n] = r * 256 + (p32 ^ (r & 7)) * 8;
        int d  = 8 * (w * 4 + n) + dr8;          // 0..255
        tgoff[n] = d * 4096 + (p8 ^ dr8) * 8;
    }

    const int r0 = (w4 >> 1) * 32;    // wave's i base within group
    const int c0 = (w4 & 1) * 32;     // wave's j base within tile
    const int pA = l16 & 7;

    // ---- Vi fragments in registers (64 VGPRs; GEMM1 B-operand) ----
    short8 A0[8], A1[8];
    {
        const unsigned short* ar0 = Vbb + (size_t)(it0 + g * 64 + r0 + l16) * 256 + quad * 8;
        const unsigned short* ar1 = ar0 + 16 * 256;
        #pragma unroll
        for (int ks = 0; ks < 8; ++ks) {
            A0[ks] = *(const short8*)(ar0 + ks * 32);
            A1[ks] = *(const short8*)(ar1 + ks * 32);
        }
    }

    // ---- prologue: stage tile 0 (vjt->buf0, vj, stj) ----
    #pragma unroll
    for (int n = 0; n < 4; ++n)
        gl_lds16(VTb + (size_t)jbase + tgoff[n], smem + (w * 4 + n) * 1024);
    #pragma unroll
    for (int n = 0; n < 4; ++n)
        gl_lds16(Vbb + (size_t)jbase * 256 + vgoff[n],
                 smem + 65536 + (w * 4 + n) * 1024);
    if (w == 0) gl_lds4(stb + jbase + lane, stjL);

    floatx4 dv[4][4];                 // GEMM2 acc: [i-tile][d-tile]
    #pragma unroll
    for (int a = 0; a < 4; ++a)
        #pragma unroll
        for (int c = 0; c < 4; ++c)
            dv[a][c] = (floatx4){0.f, 0.f, 0.f, 0.f};
    float dsp[2] = {0.f, 0.f};        // [ic]: i = r0 + ic*16 + l16

    for (int k = 0; k < niter; ++k) {
        const int buf = k & 1;
        unsigned short* Eshg = (unsigned short*)(smem + 98304 + g * 18432 + buf * 9216);
        unsigned short* vjtg = (unsigned short*)(smem + buf * 32768);

        __syncthreads();   // B1: vjt[buf](k), vj(k), stj(k) visible

        // ---- stage vjt(k+1) into the other buffer ----
        if (k + 1 < niter) {
            const size_t j0n = jbase + (size_t)(k + 1) * 64;
            #pragma unroll
            for (int n = 0; n < 4; ++n)
                gl_lds16(VTb + j0n + tgoff[n],
                         smem + (buf ^ 1) * 32768 + (w * 4 + n) * 1024);
        }

        // ---- GEMM1 (S^T): sa[ja][ic] = Vj(c0+ja*16) . Vi(r0+ic*16)^T ----
        floatx4 sa[2][2];
        #pragma unroll
        for (int a = 0; a < 2; ++a)
            #pragma unroll
            for (int c = 0; c < 2; ++c)
                sa[a][c] = (floatx4){0.f, 0.f, 0.f, 0.f};

        #pragma unroll
        for (int ks = 0; ks < 8; ++ks) {
            const int p = ((ks * 4 + quad) ^ pA) * 8;
            short8 aj0 = *(const short8*)&vjL[(c0 + l16) * 256 + p];
            short8 aj1 = *(const short8*)&vjL[(c0 + 16 + l16) * 256 + p];
            sa[0][0] = __builtin_amdgcn_mfma_f32_16x16x32_bf16(aj0, A0[ks], sa[0][0], 0, 0, 0);
            sa[0][1] = __builtin_amdgcn_mfma_f32_16x16x32_bf16(aj0, A1[ks], sa[0][1], 0, 0, 0);
            sa[1][0] = __builtin_amdgcn_mfma_f32_16x16x32_bf16(aj1, A0[ks], sa[1][0], 0, 0, 0);
            sa[1][1] = __builtin_amdgcn_mfma_f32_16x16x32_bf16(aj1, A1[ks], sa[1][1], 0, 0, 0);
        }

        // ---- softsign epilogue: e = s/(16+|s|) -> Esh b64 writes + ds ----
        // lane holds E[i = r0+ic*16+l16][j = c0+ja*16+quad*4+r]
        float4 stq[2];
        stq[0] = *(const float4*)&stjL[c0 + quad * 4];
        stq[1] = *(const float4*)&stjL[c0 + 16 + quad * 4];
        #pragma unroll
        for (int ja = 0; ja < 2; ++ja) {
            #pragma unroll
            for (int ic = 0; ic < 2; ++ic) {
                float e0 = sa[ja][ic][0] * __builtin_amdgcn_rcpf(16.0f + fabsf(sa[ja][ic][0]));
                float e1 = sa[ja][ic][1] * __builtin_amdgcn_rcpf(16.0f + fabsf(sa[ja][ic][1]));
                float e2 = sa[ja][ic][2] * __builtin_amdgcn_rcpf(16.0f + fabsf(sa[ja][ic][2]));
                float e3 = sa[ja][ic][3] * __builtin_amdgcn_rcpf(16.0f + fabsf(sa[ja][ic][3]));
                dsp[ic] += e0 * stq[ja].x + e1 * stq[ja].y + e2 * stq[ja].z + e3 * stq[ja].w;
                uint2 pk;
                pk.x = (unsigned int)f2bf(e0) | ((unsigned int)f2bf(e1) << 16);
                pk.y = (unsigned int)f2bf(e2) | ((unsigned int)f2bf(e3) << 16);
                *(uint2*)&Eshg[(r0 + ic * 16 + l16) * 72 + c0 + ja * 16 + quad * 4] = pk;
            }
        }
        __syncthreads();   // B2: Esh[buf] visible; vj/stj consumed; vjt DMA drained

        // ---- stage vj(k+1)/stj(k+1) (single buffer; window: GEMM2) ----
        if (k + 1 < niter) {
            const size_t j0n = jbase + (size_t)(k + 1) * 64;
            #pragma unroll
            for (int n = 0; n < 4; ++n)
                gl_lds16(Vbb + j0n * 256 + vgoff[n],
                         smem + 65536 + (w * 4 + n) * 1024);
            if (w == 0) gl_lds4(stb + j0n + lane, stjL);
        }

        // ---- GEMM2: dval += E . Vj (A from Esh[buf], B from vjt[buf]) ----
        #pragma unroll
        for (int ks = 0; ks < 2; ++ks) {
            short8 af[4], bfr[4];
            #pragma unroll
            for (int a2 = 0; a2 < 4; ++a2)
                af[a2] = *(const short8*)&Eshg[(a2 * 16 + l16) * 72 + ks * 32 + quad * 8];
            #pragma unroll
            for (int c2 = 0; c2 < 4; ++c2) {
                const int d = w4 * 64 + c2 * 16 + l16;
                const int p = ((ks * 4 + quad) ^ pA) * 8;
                bfr[c2] = *(const short8*)&vjtg[d * 64 + p];
            }
            #pragma unroll
            for (int a2 = 0; a2 < 4; ++a2)
                #pragma unroll
                for (int c2 = 0; c2 < 4; ++c2)
                    dv[a2][c2] = __builtin_amdgcn_mfma_f32_16x16x32_bf16(af[a2], bfr[c2], dv[a2][c2], 0, 0, 0);
        }
        // next barrier is B1 of iter k+1
    }

    // ---- epilogue: partial delta_val (R6 verbatim) ----
    float* dvo = dvp + (size_t)jh * B_ * N_ * D_ + (size_t)b * N_ * D_
                     + (size_t)(it0 + g * 64) * D_;
    #pragma unroll
    for (int a2 = 0; a2 < 4; ++a2)
        #pragma unroll
        for (int c2 = 0; c2 < 4; ++c2)
            #pragma unroll
            for (int r = 0; r < 4; ++r) {
                const int il = a2 * 16 + quad * 4 + r;
                const int d  = w4 * 64 + c2 * 16 + l16;
                dvo[(size_t)il * D_ + d] = dv[a2][c2][r];
            }

    // ---- epilogue: partial delta_state ----
    // dsp[ic] covers i = r0+ic*16+l16 over this wave's quad-sliced 8 j of 32;
    // reduce over the 4 quads (lanes l16, l16+16, l16+32, l16+48).
    #pragma unroll
    for (int ic = 0; ic < 2; ++ic) {
        float v = dsp[ic];
        v += __shfl_xor(v, 16);
        v += __shfl_xor(v, 32);
        dsp[ic] = v;
    }
    if (quad == 0) {
        #pragma unroll
        for (int ic = 0; ic < 2; ++ic)
            dsredg[(w4 & 1) * 64 + r0 + ic * 16 + l16] = dsp[ic];
    }
    __syncthreads();
    if (t < 128) {
        const int gg = t >> 6;
        const int i  = t & 63;
        const float* dsr = (const float*)(smem + 135424 + gg * 512);
        dsp_o[(size_t)jh * B_ * N_ + (size_t)b * N_ + it0 + gg * 64 + i]
            = dsr[i] + dsr[64 + i];
    }
}

// ---------------- combine: out = sum of the two j-half partials ----------------
__global__ __launch_bounds__(256)
void combine_kernel(const float4* __restrict__ dv0, const float4* __restrict__ dv1,
                    const float*  __restrict__ ds0, const float*  __restrict__ ds1,
                    float* __restrict__ out) {
    const int NDV4 = B_ * N_ * D_ / 4;   // 1048576
    const int NDS  = B_ * N_;            // 16384
    int x = blockIdx.x * 256 + threadIdx.x;
    if (x < NDV4) {
        float4 a = dv0[x], c = dv1[x];
        float4 r;
        r.x = a.x + c.x; r.y = a.y + c.y; r.z = a.z + c.z; r.w = a.w + c.w;
        ((float4*)(out + NDS))[x] = r;
    } else {
        int y = (x - NDV4) * 4;
        if (y < NDS) {
            float4 a = *(const float4*)(ds0 + y);
            float4 c = *(const float4*)(ds1 + y);
            float4 r;
            r.x = a.x + c.x; r.y = a.y + c.y; r.z = a.z + c.z; r.w = a.w + c.w;
            *(float4*)(out + y) = r;
        }
    }
}

// ---------------- fallback (round-1 kernel, used if ws too small) ----------------
__global__ __launch_bounds__(256, 1)
void prop_kernel_fb(const float* __restrict__ val,
                    const float* __restrict__ state,
                    float* __restrict__ out) {
    __shared__ __attribute__((aligned(16))) unsigned short vi[64][264];
    __shared__ __attribute__((aligned(16))) unsigned short vj[64][264];
    __shared__ __attribute__((aligned(16))) unsigned short vjt[2048][8];
    __shared__ __attribute__((aligned(16))) unsigned short Esh[64][72];
    __shared__ float stj[64];
    __shared__ float dsred[2][64];

    const int t    = threadIdx.x;
    const int w    = t >> 6;
    const int lane = t & 63;
    const int quad = lane >> 4;
    const int l16  = lane & 15;
    const int b   = blockIdx.x >> 6;
    const int it0 = (blockIdx.x & 63) << 6;
    const float* valb = val   + (size_t)b * N_ * D_;
    const float* stb  = state + (size_t)b * N_;

    #pragma unroll
    for (int n = 0; n < 16; ++n) {
        int idx = t + 256 * n;
        int row = idx >> 6;
        int c4  = idx & 63;
        float4 v = *(const float4*)(valb + (size_t)(it0 + row) * D_ + c4 * 4);
        ushort4 h;
        h.x = f2bf(v.x); h.y = f2bf(v.y); h.z = f2bf(v.z); h.w = f2bf(v.w);
        *(ushort4*)&vi[row][c4 * 4] = h;
    }

    const int r0 = (w >> 1) * 32;
    const int c0 = (w & 1) * 32;
    floatx4 dv[4][4];
    #pragma unroll
    for (int a = 0; a < 4; ++a)
        #pragma unroll
        for (int c = 0; c < 4; ++c)
            dv[a][c] = (floatx4){0.f, 0.f, 0.f, 0.f};
    float dsp[8];
    #pragma unroll
    for (int k = 0; k < 8; ++k) dsp[k] = 0.f;

    for (int jt = 0; jt < 64; ++jt) {
        const int j0 = jt * 64;
        #pragma unroll
        for (int n = 0; n < 16; ++n) {
            int idx = t + 256 * n;
            int row = idx >> 6;
            int c4  = idx & 63;
            float4 v = *(const float4*)(valb + (size_t)(j0 + row) * D_ + c4 * 4);
            ushort4 h;
            h.x = f2bf(v.x); h.y = f2bf(v.y); h.z = f2bf(v.z); h.w = f2bf(v.w);
            *(ushort4*)&vj[row][c4 * 4] = h;
        }
        if (t < 64) stj[t] = stb[j0 + t];
        __syncthreads();

        #pragma unroll
        for (int n = 0; n < 8; ++n) {
            const int d  = t;
            const int jb = n;
            short8 pk;
            #pragma unroll
            for (int jj = 0; jj < 8; ++jj) pk[jj] = (short)vj[jb * 8 + jj][d];
            *(short8*)&vjt[d * 8 + (jb ^ (d & 7))][0] = pk;
        }

        floatx4 sa[2][2];
        #pragma unroll
        for (int a = 0; a < 2; ++a)
            #pragma unroll
            for (int c = 0; c < 2; ++c)
                sa[a][c] = (floatx4){0.f, 0.f, 0.f, 0.f};
        #pragma unroll
        for (int ks = 0; ks < 8; ++ks) {
            const int d0 = ks * 32 + quad * 8;
            short8 a0 = *(const short8*)&vi[r0 + l16][d0];
            short8 a1 = *(const short8*)&vi[r0 + 16 + l16][d0];
            short8 b0 = *(const short8*)&vj[c0 + l16][d0];
            short8 b1 = *(const short8*)&vj[c0 + 16 + l16][d0];
            sa[0][0] = __builtin_amdgcn_mfma_f32_16x16x32_bf16(a0, b0, sa[0][0], 0, 0, 0);
            sa[0][1] = __builtin_amdgcn_mfma_f32_16x16x32_bf16(a0, b1, sa[0][1], 0, 0, 0);
            sa[1][0] = __builtin_amdgcn_mfma_f32_16x16x32_bf16(a1, b0, sa[1][0], 0, 0, 0);
            sa[1][1] = __builtin_amdgcn_mfma_f32_16x16x32_bf16(a1, b1, sa[1][1], 0, 0, 0);
        }

        float stc0 = stj[c0 + l16];
        float stc1 = stj[c0 + 16 + l16];
        #pragma unroll
        for (int a = 0; a < 2; ++a) {
            #pragma unroll
            for (int r = 0; r < 4; ++r) {
                const int il = r0 + a * 16 + quad * 4 + r;
                float s0 = sa[a][0][r] * 0.0625f;
                float s1 = sa[a][1][r] * 0.0625f;
                float e0 = s0 / (1.0f + fabsf(s0));
                float e1 = s1 / (1.0f + fabsf(s1));
                dsp[a * 4 + r] += e0 * stc0 + e1 * stc1;
                Esh[il][c0 + l16]      = f2bf(e0);
                Esh[il][c0 + 16 + l16] = f2bf(e1);
            }
        }
        __syncthreads();

        #pragma unroll
        for (int ks = 0; ks < 2; ++ks) {
            short8 af[4], bfr[4];
            #pragma unroll
            for (int a2 = 0; a2 < 4; ++a2)
                af[a2] = *(const short8*)&Esh[a2 * 16 + l16][ks * 32 + quad * 8];
            #pragma unroll
            for (int c2 = 0; c2 < 4; ++c2) {
                const int d  = w * 64 + c2 * 16 + l16;
                const int jb = ks * 4 + quad;
                bfr[c2] = *(const short8*)&vjt[d * 8 + (jb ^ (d & 7))][0];
            }
            #pragma unroll
            for (int a2 = 0; a2 < 4; ++a2)
                #pragma unroll
                for (int c2 = 0; c2 < 4; ++c2)
                    dv[a2][c2] = __builtin_amdgcn_mfma_f32_16x16x32_bf16(af[a2], bfr[c2], dv[a2][c2], 0, 0, 0);
        }
    }

    float* dvo = out + (size_t)B_ * N_ + (size_t)b * N_ * D_;
    #pragma unroll
    for (int a2 = 0; a2 < 4; ++a2)
        #pragma unroll
        for (int c2 = 0; c2 < 4; ++c2)
            #pragma unroll
            for (int r = 0; r < 4; ++r) {
                const int i = it0 + a2 * 16 + quad * 4 + r;
                const int d = w * 64 + c2 * 16 + l16;
                dvo[(size_t)i * D_ + d] = dv[a2][c2][r];
            }

    #pragma unroll
    for (int k = 0; k < 8; ++k) {
        float v = dsp[k];
        v += __shfl_xor(v, 1);
        v += __shfl_xor(v, 2);
        v += __shfl_xor(v, 4);
        v += __shfl_xor(v, 8);
        dsp[k] = v;
    }
    if (l16 == 0) {
        #pragma unroll
        for (int a = 0; a < 2; ++a)
            #pragma unroll
            for (int r = 0; r < 4; ++r) {
                const int row = (w >> 1) * 32 + a * 16 + quad * 4 + r;
                dsred[w & 1][row] = dsp[a * 4 + r];
            }
    }
    __syncthreads();
    if (t < 64) out[(size_t)b * N_ + it0 + t] = dsred[0][t] + dsred[1][t];
}

extern "C" void kernel_launch(void* const* d_in, const int* in_sizes, int n_in,
                              void* d_out, int out_size, void* d_ws, size_t ws_size,
                              hipStream_t stream) {
    const float* val   = (const float*)d_in[0];
    const float* state = (const float*)d_in[1];
    float* out = (float*)d_out;

    const size_t nE         = (size_t)B_ * N_ * D_;                 // 4,194,304
    const size_t need_base  = 2 * nE * sizeof(unsigned short);      // 16.78 MB
    const size_t need_split = need_base + 2 * nE * sizeof(float)
                            + 2 * (size_t)B_ * N_ * sizeof(float);  // ~50.5 MB

    if (ws_size >= need_split) {
        unsigned short* Vb = (unsigned short*)d_ws;
        unsigned short* VT = Vb + nE;
        float* dvp = (float*)(VT + nE);          // [2][B*N*D]
        float* dsp = dvp + 2 * nE;               // [2][B*N]
        prepass_kernel<<<dim3(1024), dim3(256), 0, stream>>>(val, Vb, VT);
        prop_main<<<dim3(256), dim3(512), 0, stream>>>(state, Vb, VT, dvp, dsp);
        const int NDV4 = B_ * N_ * D_ / 4;
        const int NDS4 = B_ * N_ / 4;
        combine_kernel<<<dim3((NDV4 + NDS4) / 256), dim3(256), 0, stream>>>(
            (const float4*)dvp, (const float4*)(dvp + nE),
            dsp, dsp + (size_t)B_ * N_, out);
    } else {
        prop_kernel_fb<<<dim3(256), dim3(256), 0, stream>>>(val, state, out);
    }
}